// Round 4
// baseline (181.803 us; speedup 1.0000x reference)
//
#include <hip/hip_runtime.h>

// Problem constants (from reference): SEQ=512, BATCH=512, NUM_TAGS=128
#define SEQ   512
#define BATCH 512
#define NTAGS 128

// Kernel 1 geometry: grid (BATCH/64, NTILE) blocks of 256 threads.
// Each block: 64 batch lanes x 4 t-subgroups; each thread handles TPS t's.
// NTILE * 4 * TPS == SEQ  ->  32 * 4 * 4 = 512.
#define NTILE 32
#define TPS   4

__global__ __launch_bounds__(256) void crf_partial(
    const float* __restrict__ emissions,    // [SEQ][BATCH][NTAGS]
    const int*   __restrict__ tags,         // [SEQ][BATCH]
    const int*   __restrict__ mask,         // [SEQ][BATCH]
    const float* __restrict__ transitions,  // [NTAGS][NTAGS]
    float*       __restrict__ ws_score,     // [NTILE][BATCH]
    int*         __restrict__ ws_cnt)       // [NTILE][BATCH]
{
    const int lane_b = threadIdx.x & 63;        // batch lane within group
    const int sub    = threadIdx.x >> 6;        // 0..3 t-subgroup
    const int b      = blockIdx.x * 64 + lane_b;
    const int t0     = (blockIdx.y * 4 + sub) * TPS;

    float score = 0.0f;
    int   cnt   = 0;

    // Stage all per-t loads first for MLP, then combine.
    // tgv[0] = tags[t0-1] (prev tag), tgv[1+i] = tags[t0+i].
    int   tgv[TPS + 1], mk[TPS];
    float em[TPS];

    tgv[0] = (t0 > 0) ? tags[(t0 - 1) * BATCH + b] : 0;
    #pragma unroll
    for (int i = 0; i < TPS; ++i) {
        const int t = t0 + i;
        tgv[1 + i] = tags[t * BATCH + b];
        mk[i]      = mask[t * BATCH + b];
    }
    #pragma unroll
    for (int i = 0; i < TPS; ++i) {
        const int t = t0 + i;
        em[i] = emissions[(size_t)t * (BATCH * NTAGS) + b * NTAGS + tgv[1 + i]];
    }
    #pragma unroll
    for (int i = 0; i < TPS; ++i) {
        const int t = t0 + i;
        cnt += mk[i];
        if (t == 0) {
            // start term's emission is unconditional (not masked)
            score += em[i];
        } else {
            const float tr = transitions[tgv[i] * NTAGS + tgv[1 + i]];
            score += (tr + em[i]) * (float)mk[i];
        }
    }

    // Reduce the 4 t-subgroups within the block (different waves -> LDS).
    __shared__ float s_score[4][64];
    __shared__ int   s_cnt[4][64];
    s_score[sub][lane_b] = score;
    s_cnt[sub][lane_b]   = cnt;
    __syncthreads();

    if (sub == 0) {
        float tot = s_score[0][lane_b] + s_score[1][lane_b]
                  + s_score[2][lane_b] + s_score[3][lane_b];
        int ctot  = s_cnt[0][lane_b] + s_cnt[1][lane_b]
                  + s_cnt[2][lane_b] + s_cnt[3][lane_b];
        ws_score[blockIdx.y * BATCH + b] = tot;
        ws_cnt[blockIdx.y * BATCH + b]   = ctot;
    }
}

__global__ __launch_bounds__(256) void crf_final(
    const int*   __restrict__ tags,              // [SEQ][BATCH]
    const float* __restrict__ start_transitions, // [NTAGS]
    const float* __restrict__ end_transitions,   // [NTAGS]
    const float* __restrict__ ws_score,          // [NTILE][BATCH]
    const int*   __restrict__ ws_cnt,            // [NTILE][BATCH]
    float*       __restrict__ out)               // [BATCH]
{
    const int b = blockIdx.x * blockDim.x + threadIdx.x;
    if (b >= BATCH) return;

    float s   = 0.0f;
    int   cnt = 0;
    #pragma unroll
    for (int r = 0; r < NTILE; ++r) {
        s   += ws_score[r * BATCH + b];
        cnt += ws_cnt[r * BATCH + b];
    }

    int seq_end = cnt - 1;
    if (seq_end < 0) seq_end += SEQ;   // JAX negative-index wrap semantics

    const int last_tag  = tags[seq_end * BATCH + b];
    const int first_tag = tags[b];     // tags[0][b]

    out[b] = s + start_transitions[first_tag] + end_transitions[last_tag];
}

extern "C" void kernel_launch(void* const* d_in, const int* in_sizes, int n_in,
                              void* d_out, int out_size, void* d_ws, size_t ws_size,
                              hipStream_t stream) {
    const float* emissions         = (const float*)d_in[0];
    const int*   tags              = (const int*)d_in[1];
    const int*   mask              = (const int*)d_in[2];
    const float* start_transitions = (const float*)d_in[3];
    const float* end_transitions   = (const float*)d_in[4];
    const float* transitions       = (const float*)d_in[5];
    float* out = (float*)d_out;

    float* ws_score = (float*)d_ws;                       // NTILE*BATCH floats
    int*   ws_cnt   = (int*)((char*)d_ws + NTILE * BATCH * sizeof(float));

    dim3 grid1(BATCH / 64, NTILE);
    crf_partial<<<grid1, 256, 0, stream>>>(emissions, tags, mask, transitions,
                                           ws_score, ws_cnt);

    dim3 grid2((BATCH + 255) / 256);
    crf_final<<<grid2, 256, 0, stream>>>(tags, start_transitions, end_transitions,
                                         ws_score, ws_cnt, out);
}